// Round 1
// baseline (122.129 us; speedup 1.0000x reference)
//
#include <hip/hip_runtime.h>
#include <math.h>

#define NROW 16384
#define KTOP 32
#define NT 256

static constexpr float F_EPS = 1.1920928955078125e-07f;   // 2^-23 (np.float32 eps)
static constexpr float F_E2  = F_EPS * F_EPS;             // 2^-46, exact
static constexpr float F_INV_E2 = 1.0f / F_E2;            // 2^46, exact -> div == mul

__device__ __forceinline__ float max64(const float (&v)[64]) {
    float a[32];
#pragma unroll
    for (int i = 0; i < 32; ++i) a[i] = fmaxf(v[i], v[i + 32]);
#pragma unroll
    for (int i = 0; i < 16; ++i) a[i] = fmaxf(a[i], a[i + 16]);
#pragma unroll
    for (int i = 0; i < 8; ++i)  a[i] = fmaxf(a[i], a[i + 8]);
#pragma unroll
    for (int i = 0; i < 4; ++i)  a[i] = fmaxf(a[i], a[i + 4]);
    return fmaxf(fmaxf(a[0], a[1]), fmaxf(a[2], a[3]));
}

// One block per row: top-32 (sorted desc, duplicates preserved) + s[j] = 1 - x_m_sum[j]
__global__ __launch_bounds__(NT, 1)
void topk_stats_kernel(const float* __restrict__ x, float* __restrict__ t_ws,
                       float* __restrict__ s_ws) {
    __shared__ float row[NROW];          // pristine copy of the row
    __shared__ float red[4];
    __shared__ float tvals[KTOP];
    __shared__ int   winTid;
    __shared__ float partial[4][KTOP];

    const int tid = threadIdx.x;
    const int b   = blockIdx.x;
    const float4* __restrict__ x4 = (const float4*)(x + (size_t)b * NROW);
    float4* row4 = (float4*)row;

    // load row: registers (working copy) + LDS (pristine copy)
    float v[64];
#pragma unroll
    for (int i = 0; i < 16; ++i) {
        float4 w = x4[i * NT + tid];
        row4[i * NT + tid] = w;
        v[4 * i + 0] = w.x; v[4 * i + 1] = w.y;
        v[4 * i + 2] = w.z; v[4 * i + 3] = w.w;
    }
    float m = max64(v);     // per-thread running max, maintained incrementally
    __syncthreads();

#pragma unroll 1
    for (int it = 0; it < KTOP; ++it) {
        // block-wide max of per-thread maxima
        float wm = m;
#pragma unroll
        for (int off = 32; off; off >>= 1) wm = fmaxf(wm, __shfl_xor(wm, off));
        if ((tid & 63) == 0) red[tid >> 6] = wm;
        if (tid == 0) winTid = 0x7fffffff;
        __syncthreads();
        const float g = fmaxf(fmaxf(red[0], red[1]), fmaxf(red[2], red[3]));
        if (m == g) atomicMin(&winTid, tid);   // lowest-tid holder wins
        __syncthreads();
        if (tid == winTid) {
            // remove exactly one occurrence of g from this thread's registers
            bool done = false;
#pragma unroll
            for (int i = 0; i < 64; ++i) {
                if (!done && v[i] == g) { v[i] = -INFINITY; done = true; }
            }
            m = max64(v);                       // refresh local max
        }
        if (tid == 0) tvals[it] = g;
        __syncthreads();
    }

    // x_m_sum over the pristine row; only values near/above t[31] can contribute
    float tr[KTOP];
#pragma unroll
    for (int j = 0; j < KTOP; ++j) tr[j] = tvals[j];
    const float guard = tr[KTOP - 1] - 2.0f * F_EPS;

    float acc[KTOP];
#pragma unroll
    for (int j = 0; j < KTOP; ++j) acc[j] = 0.0f;

#pragma unroll 1
    for (int i = 0; i < 16; ++i) {
        float4 w = row4[i * NT + tid];
        float e[4] = {w.x, w.y, w.z, w.w};
#pragma unroll
        for (int c = 0; c < 4; ++c) {
            float vv = e[c];
            if (vv >= guard) {                  // rare (~32 of 16384 per row)
#pragma unroll
                for (int j = 0; j < KTOP; ++j) {
                    float d = vv - tr[j];
                    acc[j] += fmaxf(F_E2 - d * d, 0.0f) * F_INV_E2;
                }
            }
        }
    }

    // deterministic block reduction of acc[j]
#pragma unroll
    for (int j = 0; j < KTOP; ++j) {
        float a = acc[j];
#pragma unroll
        for (int off = 32; off; off >>= 1) a += __shfl_xor(a, off);
        acc[j] = a;
    }
    const int lane = tid & 63, wave = tid >> 6;
    if (lane == 0) {
#pragma unroll
        for (int j = 0; j < KTOP; ++j) partial[wave][j] = acc[j];
    }
    __syncthreads();
    if (tid < KTOP) {
        float s = partial[0][tid] + partial[1][tid] + partial[2][tid] + partial[3][tid];
        t_ws[b * KTOP + tid] = tvals[tid];
        s_ws[b * KTOP + tid] = 1.0f - s;        // out = relu(x_m + s)
    }
}

// Streaming writer: one float4 (4 j's of one (b,n)) per thread; fully coalesced.
__global__ __launch_bounds__(NT)
void write_out_kernel(const float* __restrict__ x, const float* __restrict__ t_ws,
                      const float* __restrict__ s_ws, float4* __restrict__ out) {
    const size_t f4 = (size_t)blockIdx.x * NT + threadIdx.x;
    const int b     = (int)(f4 >> 17);          // NROW * KTOP/4 = 131072 f4 per row
    const int inner = (int)(f4 & 131071);
    const int n     = inner >> 3;               // 8 f4 per (b,n)
    const int jq    = inner & 7;

    const float xv = x[(size_t)b * NROW + n];   // 8 lanes share -> L1 broadcast
    const float4 t = ((const float4*)(t_ws + b * KTOP))[jq];
    const float4 s = ((const float4*)(s_ws + b * KTOP))[jq];

    float4 o; float d, mm;
    d = xv - t.x; mm = fmaxf(F_E2 - d * d, 0.0f) * F_INV_E2; o.x = fmaxf(mm + s.x, 0.0f);
    d = xv - t.y; mm = fmaxf(F_E2 - d * d, 0.0f) * F_INV_E2; o.y = fmaxf(mm + s.y, 0.0f);
    d = xv - t.z; mm = fmaxf(F_E2 - d * d, 0.0f) * F_INV_E2; o.z = fmaxf(mm + s.z, 0.0f);
    d = xv - t.w; mm = fmaxf(F_E2 - d * d, 0.0f) * F_INV_E2; o.w = fmaxf(mm + s.w, 0.0f);
    out[f4] = o;
}

extern "C" void kernel_launch(void* const* d_in, const int* in_sizes, int n_in,
                              void* d_out, int out_size, void* d_ws, size_t ws_size,
                              hipStream_t stream) {
    const float* x = (const float*)d_in[0];
    const int B = in_sizes[0] / NROW;           // 128
    float* t_ws = (float*)d_ws;
    float* s_ws = t_ws + B * KTOP;

    topk_stats_kernel<<<B, NT, 0, stream>>>(x, t_ws, s_ws);

    const int total_f4 = out_size / 4;          // 16,777,216
    const int blocks   = total_f4 / NT;         // 65,536
    write_out_kernel<<<blocks, NT, 0, stream>>>(x, t_ws, s_ws, (float4*)d_out);
}

// Round 2
// 119.998 us; speedup vs baseline: 1.0178x; 1.0178x over previous
//
#include <hip/hip_runtime.h>
#include <math.h>

#define NROW 16384
#define KTOP 32
#define NT   256
#define ZPF4 16              // float4 zero-stores per thread in zero blocks

static constexpr float F_EPS    = 1.1920928955078125e-07f;  // 2^-23 (np.float32 eps)
static constexpr float F_E2     = F_EPS * F_EPS;            // 2^-46, exact
static constexpr float F_INV_E2 = 1.0f / F_E2;              // 2^46, exact -> div == mul

// monotone fp32 -> uint32 (order-preserving): larger float <=> larger uint
__device__ __forceinline__ unsigned int f2u(float f) {
    unsigned int b = __float_as_uint(f);
    return (b & 0x80000000u) ? ~b : (b | 0x80000000u);
}
__device__ __forceinline__ float u2f(unsigned int u) {
    unsigned int b = (u & 0x80000000u) ? (u ^ 0x80000000u) : ~u;
    return __uint_as_float(b);
}

// blocks [0, B): per-row radix-select top-32 + s[j] = 1 - x_m_sum[j]  -> ts ws
// blocks [B, B+ZB): stream float4 zeros into out
__global__ __launch_bounds__(NT)
void topk_zero_kernel(const float* __restrict__ x, float* __restrict__ out,
                      float* __restrict__ ts, int B) {
    __shared__ unsigned int hist[4][256];
    __shared__ unsigned int sel[2];       // [0]=digit, [1]=remaining k inside bin
    __shared__ unsigned int gtList[KTOP];
    __shared__ unsigned int gtCount;
    __shared__ unsigned int tU[KTOP];
    __shared__ float tFs[KTOP];
    __shared__ float svals[KTOP];

    const int tid = threadIdx.x;

    if (blockIdx.x >= B) {
        // ---- zero-streaming path ----
        const size_t zb   = (size_t)(blockIdx.x - B);
        float4* __restrict__ o4 = (float4*)out;
        const size_t base = zb * (NT * ZPF4) + tid;
        const float4 z = make_float4(0.f, 0.f, 0.f, 0.f);
#pragma unroll
        for (int i = 0; i < ZPF4; ++i) o4[base + (size_t)i * NT] = z;
        return;
    }

    // ---- per-row top-k path ----
    const int b = blockIdx.x;
    const float4* __restrict__ x4 = (const float4*)(x + (size_t)b * NROW);

    unsigned int u[64];
#pragma unroll
    for (int i = 0; i < 16; ++i) {
        float4 w = x4[i * NT + tid];
        u[4*i+0] = f2u(w.x); u[4*i+1] = f2u(w.y);
        u[4*i+2] = f2u(w.z); u[4*i+3] = f2u(w.w);
    }
    const int wv = tid >> 6;

    unsigned int prefix = 0, k = KTOP;
    // pass 0 (bits 31..24)
    hist[0][tid] = 0; hist[1][tid] = 0; hist[2][tid] = 0; hist[3][tid] = 0;
    __syncthreads();
#pragma unroll
    for (int i = 0; i < 64; ++i) atomicAdd(&hist[wv][u[i] >> 24], 1u);
    __syncthreads();
    hist[0][tid] += hist[1][tid] + hist[2][tid] + hist[3][tid];
    __syncthreads();
    if (tid == 0) {
        unsigned int cum = 0;
        for (int bin = 255; bin >= 0; --bin) {
            unsigned int h = hist[0][bin];
            if (cum + h >= k) { sel[0] = (unsigned)bin; sel[1] = k - cum; break; }
            cum += h;
        }
    }
    __syncthreads();
    prefix = sel[0]; k = sel[1];

    // passes 1..3 (bits 23..16, 15..8, 7..0)
    for (int d = 16; d >= 0; d -= 8) {
        __syncthreads();
        hist[0][tid] = 0; hist[1][tid] = 0; hist[2][tid] = 0; hist[3][tid] = 0;
        __syncthreads();
#pragma unroll
        for (int i = 0; i < 64; ++i) {
            if ((u[i] >> (d + 8)) == prefix)
                atomicAdd(&hist[wv][(u[i] >> d) & 255u], 1u);
        }
        __syncthreads();
        hist[0][tid] += hist[1][tid] + hist[2][tid] + hist[3][tid];
        __syncthreads();
        if (tid == 0) {
            unsigned int cum = 0;
            for (int bin = 255; bin >= 0; --bin) {
                unsigned int h = hist[0][bin];
                if (cum + h >= k) { sel[0] = (unsigned)bin; sel[1] = k - cum; break; }
                cum += h;
            }
        }
        __syncthreads();
        prefix = (prefix << 8) | sel[0]; k = sel[1];
    }

    const unsigned int T   = prefix;      // 32nd-largest value (uint domain)
    const unsigned int cgt = KTOP - k;    // count strictly greater than T

    if (tid == 0) gtCount = 0;
    __syncthreads();
#pragma unroll
    for (int i = 0; i < 64; ++i) {
        if (u[i] > T) { unsigned int idx = atomicAdd(&gtCount, 1u); gtList[idx] = u[i]; }
    }
    __syncthreads();

    // rank-sort the <=31 strictly-greater values; pad tail with T copies
    if (tid < KTOP) {
        if (tid < (int)cgt) {
            unsigned int v = gtList[tid];
            int r = 0;
            for (int j = 0; j < (int)cgt; ++j) {
                unsigned int w2 = gtList[j];
                if (w2 > v || (w2 == v && j < tid)) ++r;
            }
            tU[r] = v;
        } else {
            tU[tid] = T;
        }
    }
    __syncthreads();
    if (tid < KTOP) { tFs[tid] = u2f(tU[tid]); svals[tid] = 0.0f; }
    __syncthreads();

    // x_m_sum: only values near/above t[31] can contribute (rare -> LDS atomics)
    const float guard = tFs[KTOP - 1] - 2.0f * F_EPS;
#pragma unroll
    for (int i = 0; i < 64; ++i) {
        float vv = u2f(u[i]);
        if (vv >= guard) {
            for (int j = 0; j < KTOP; ++j) {
                float dd = vv - tFs[j];
                float xm = fmaxf(F_E2 - dd * dd, 0.0f) * F_INV_E2;
                if (xm > 0.0f) atomicAdd(&svals[j], xm);
            }
        }
    }
    __syncthreads();

    if (tid < KTOP) {
        float* wrow = ts + (size_t)b * (2 * KTOP);
        wrow[tid]        = tFs[tid];
        wrow[KTOP + tid] = 1.0f - svals[tid];    // out = relu(x_m + s)
    }
}

// Rewrite the 128-B output row of every candidate position (everything else is 0).
__global__ __launch_bounds__(NT)
void scatter_kernel(const float* __restrict__ x, const float* __restrict__ ts,
                    float* __restrict__ out) {
    __shared__ float tFs[KTOP];
    __shared__ float svals[KTOP];
    const int b = blockIdx.x, tid = threadIdx.x;
    if (tid < 2 * KTOP) {
        float v = ts[(size_t)b * (2 * KTOP) + tid];
        if (tid < KTOP) tFs[tid] = v; else svals[tid - KTOP] = v;
    }
    __syncthreads();
    const float guard = tFs[KTOP - 1] - 2.0f * F_EPS;
    const float4* __restrict__ x4 = (const float4*)(x + (size_t)b * NROW);

#pragma unroll 1
    for (int i = 0; i < 16; ++i) {
        float4 w = x4[i * NT + tid];
        float e[4] = {w.x, w.y, w.z, w.w};
#pragma unroll
        for (int c = 0; c < 4; ++c) {
            float vv = e[c];
            if (vv >= guard) {
                const int n = (i * NT + tid) * 4 + c;
                float4* o4 = (float4*)(out + ((size_t)b * NROW + n) * KTOP);
#pragma unroll
                for (int q = 0; q < 8; ++q) {
                    float4 o; float dd, mm;
                    dd = vv - tFs[4*q+0]; mm = fmaxf(F_E2 - dd*dd, 0.f) * F_INV_E2; o.x = fmaxf(mm + svals[4*q+0], 0.f);
                    dd = vv - tFs[4*q+1]; mm = fmaxf(F_E2 - dd*dd, 0.f) * F_INV_E2; o.y = fmaxf(mm + svals[4*q+1], 0.f);
                    dd = vv - tFs[4*q+2]; mm = fmaxf(F_E2 - dd*dd, 0.f) * F_INV_E2; o.z = fmaxf(mm + svals[4*q+2], 0.f);
                    dd = vv - tFs[4*q+3]; mm = fmaxf(F_E2 - dd*dd, 0.f) * F_INV_E2; o.w = fmaxf(mm + svals[4*q+3], 0.f);
                    o4[q] = o;
                }
            }
        }
    }
}

extern "C" void kernel_launch(void* const* d_in, const int* in_sizes, int n_in,
                              void* d_out, int out_size, void* d_ws, size_t ws_size,
                              hipStream_t stream) {
    const float* x = (const float*)d_in[0];
    float* out = (float*)d_out;
    const int B = in_sizes[0] / NROW;                 // 128
    float* ts = (float*)d_ws;                        // B * 64 floats

    const int total_f4 = out_size / 4;               // 16,777,216
    const int ZB = total_f4 / (NT * ZPF4);           // 4096 zero blocks

    topk_zero_kernel<<<B + ZB, NT, 0, stream>>>(x, out, ts, B);
    scatter_kernel<<<B, NT, 0, stream>>>(x, ts, out);
}

// Round 3
// 109.349 us; speedup vs baseline: 1.1169x; 1.0974x over previous
//
#include <hip/hip_runtime.h>
#include <math.h>

#define NROW 16384
#define KTOP 32
#define NT   256
#define ZPF4 16          // float4 stores per thread in the writer kernel
#define CAP  4096        // candidate list capacity (worst realistic ~450)

static constexpr float F_EPS    = 1.1920928955078125e-07f;  // 2^-23
static constexpr float F_E2     = F_EPS * F_EPS;            // 2^-46 exact
static constexpr float F_INV_E2 = 1.0f / F_E2;              // 2^46 exact

// monotone fp32 <-> uint32 (order-preserving)
__device__ __forceinline__ unsigned f2u(float f) {
    unsigned b = __float_as_uint(f);
    return (b & 0x80000000u) ? ~b : (b | 0x80000000u);
}
__device__ __forceinline__ float u2f(unsigned u) {
    unsigned b = (u & 0x80000000u) ? (u ^ 0x80000000u) : ~u;
    return __uint_as_float(b);
}

// One block per row. Fully parallel top-32: single 8-bit histogram pass +
// parallel suffix-scan + candidate-list rank-sort. Then s[j] = 1 - x_m_sum[j].
__global__ __launch_bounds__(NT)
void topk_kernel(const float* __restrict__ x, float* __restrict__ ts) {
    __shared__ unsigned hist[4][256];
    __shared__ unsigned suf[257];
    __shared__ unsigned list[CAP];
    __shared__ unsigned cnt;
    __shared__ unsigned selB;
    __shared__ unsigned tU[KTOP];
    __shared__ float    tFs[KTOP];
    __shared__ float    svals[KTOP];

    const int tid = threadIdx.x;
    const int b   = blockIdx.x;
    const float4* __restrict__ x4 = (const float4*)(x + (size_t)b * NROW);

    hist[0][tid] = 0; hist[1][tid] = 0; hist[2][tid] = 0; hist[3][tid] = 0;
    if (tid == 0) { cnt = 0; suf[256] = 0; }

    unsigned u[64];
#pragma unroll
    for (int i = 0; i < 16; ++i) {
        float4 w = x4[i * NT + tid];
        u[4*i+0] = f2u(w.x); u[4*i+1] = f2u(w.y);
        u[4*i+2] = f2u(w.z); u[4*i+3] = f2u(w.w);
    }
    __syncthreads();

    const int wv = tid >> 6;
#pragma unroll
    for (int i = 0; i < 64; ++i) atomicAdd(&hist[wv][u[i] >> 24], 1u);
    __syncthreads();

    suf[tid] = hist[0][tid] + hist[1][tid] + hist[2][tid] + hist[3][tid];
    __syncthreads();

    // parallel inclusive suffix-sum: suf[t] = # values with top byte >= t
#pragma unroll
    for (int off = 1; off < 256; off <<= 1) {
        unsigned add = (tid + off < 256) ? suf[tid + off] : 0;
        __syncthreads();
        suf[tid] += add;
        __syncthreads();
    }
    if (suf[tid] >= KTOP && suf[tid + 1] < KTOP) selB = (unsigned)tid;  // unique
    __syncthreads();

    const unsigned thrU = selB << 24;
#pragma unroll
    for (int i = 0; i < 64; ++i) {
        if (u[i] >= thrU) {
            unsigned p = atomicAdd(&cnt, 1u);
            if (p < CAP) list[p] = u[i];
        }
    }
    __syncthreads();

    const int C = (int)min(cnt, (unsigned)CAP);   // >= 32 by construction
    // rank-sort: exact top-32 with deterministic tie-break by list position
    for (int p = tid; p < C; p += NT) {
        unsigned v = list[p];
        int r = 0;
        for (int j = 0; j < C; ++j) {
            unsigned w = list[j];
            r += (w > v) || (w == v && j < p);
        }
        if (r < KTOP) tU[r] = v;
    }
    __syncthreads();
    if (tid < KTOP) { tFs[tid] = u2f(tU[tid]); svals[tid] = 0.0f; }
    __syncthreads();

    // x_m_sum: only x >= t[31] - 2eps can contribute; sweep register copy.
    const unsigned gU = f2u(tFs[KTOP - 1] - 2.0f * F_EPS);
#pragma unroll
    for (int i = 0; i < 64; ++i) {
        if (u[i] >= gU) {
            float vv = u2f(u[i]);
            for (int j = 0; j < KTOP; ++j) {
                float d  = vv - tFs[j];
                float xm = fmaxf(F_E2 - d * d, 0.0f) * F_INV_E2;  // 0 or 1 here
                if (xm > 0.0f) atomicAdd(&svals[j], xm);
            }
        }
    }
    __syncthreads();

    if (tid < KTOP)            ts[b * 2 * KTOP + tid] = tFs[tid];
    else if (tid < 2 * KTOP)   ts[b * 2 * KTOP + tid] = 1.0f - svals[tid - KTOP];
}

// Streaming writer with fused scatter: each block covers 4096 contiguous float4
// of one row's output. Zero everywhere except candidate positions (x >= guard),
// which get the full formula inline. Output written exactly once.
__global__ __launch_bounds__(NT)
void write_kernel(const float* __restrict__ x, const float* __restrict__ ts,
                  float4* __restrict__ out) {
    __shared__ float tsRow[2 * KTOP];
    const int blk = blockIdx.x;
    const int b   = blk >> 5;                 // 32 blocks per row (131072 f4/row)
    const int tid = threadIdx.x;
    if (tid < 2 * KTOP) tsRow[tid] = ts[b * 2 * KTOP + tid];
    __syncthreads();

    const unsigned gU = f2u(tsRow[KTOP - 1] - 2.0f * F_EPS);
    const float* __restrict__ xrow = x + (size_t)b * NROW;
    const size_t base = (size_t)blk * (NT * ZPF4) + tid;

#pragma unroll
    for (int i = 0; i < ZPF4; ++i) {
        const size_t f4  = base + (size_t)i * NT;
        const int inner  = (int)(f4 & 131071);
        const int n      = inner >> 3;        // 8 f4 per (b,n)
        const int jq     = inner & 7;
        const float xv   = xrow[n];           // 8 lanes share -> coalesced 32B/wave
        float4 o = make_float4(0.f, 0.f, 0.f, 0.f);
        if (f2u(xv) >= gU) {                  // rare: ~32 positions per row
            const float* t = tsRow + 4 * jq;
            const float* s = tsRow + KTOP + 4 * jq;
            float d, mm;
            d = xv - t[0]; mm = fmaxf(F_E2 - d*d, 0.f) * F_INV_E2; o.x = fmaxf(mm + s[0], 0.f);
            d = xv - t[1]; mm = fmaxf(F_E2 - d*d, 0.f) * F_INV_E2; o.y = fmaxf(mm + s[1], 0.f);
            d = xv - t[2]; mm = fmaxf(F_E2 - d*d, 0.f) * F_INV_E2; o.z = fmaxf(mm + s[2], 0.f);
            d = xv - t[3]; mm = fmaxf(F_E2 - d*d, 0.f) * F_INV_E2; o.w = fmaxf(mm + s[3], 0.f);
        }
        out[f4] = o;
    }
}

extern "C" void kernel_launch(void* const* d_in, const int* in_sizes, int n_in,
                              void* d_out, int out_size, void* d_ws, size_t ws_size,
                              hipStream_t stream) {
    const float* x = (const float*)d_in[0];
    const int B = in_sizes[0] / NROW;            // 128
    float* ts = (float*)d_ws;                    // B * 64 floats

    topk_kernel<<<B, NT, 0, stream>>>(x, ts);

    const int total_f4 = out_size / 4;           // 16,777,216
    const int WB = total_f4 / (NT * ZPF4);       // 4096 blocks
    write_kernel<<<WB, NT, 0, stream>>>(x, ts, (float4*)d_out);
}

// Round 4
// 90.584 us; speedup vs baseline: 1.3482x; 1.2072x over previous
//
#include <hip/hip_runtime.h>
#include <math.h>

#define NROW 16384
#define KTOP 32
#define NT   256
#define ZPF4 16          // float4 zero-stores per thread in zero blocks
#define CAP  4096        // candidate list capacity (expected ~370 for N(0,1))

static constexpr float F_EPS    = 1.1920928955078125e-07f;  // 2^-23
static constexpr float F_E2     = F_EPS * F_EPS;            // 2^-46 exact
static constexpr float F_INV_E2 = 1.0f / F_E2;              // 2^46 exact

// monotone fp32 <-> uint32 (order-preserving)
__device__ __forceinline__ unsigned f2u(float f) {
    unsigned b = __float_as_uint(f);
    return (b & 0x80000000u) ? ~b : (b | 0x80000000u);
}
__device__ __forceinline__ float u2f(unsigned u) {
    unsigned b = (u & 0x80000000u) ? (u ^ 0x80000000u) : ~u;
    return __uint_as_float(b);
}

// blocks [0,B): per-row parallel top-32 + s[j] = 1 - x_m_sum[j]  (round-3 logic)
// blocks [B,B+ZB): PURE zero stream — no loads, no LDS use, fill-like.
__global__ __launch_bounds__(NT)
void topk_zero_kernel(const float* __restrict__ x, float4* __restrict__ out,
                      float* __restrict__ ts, int B) {
    __shared__ unsigned hist[4][256];
    __shared__ unsigned suf[257];
    __shared__ unsigned list[CAP];
    __shared__ unsigned cnt;
    __shared__ unsigned selB;
    __shared__ unsigned tU[KTOP];
    __shared__ float    tFs[KTOP];
    __shared__ float    svals[KTOP];

    const int tid = threadIdx.x;

    if (blockIdx.x >= B) {
        // ---- pure zero-streaming path: 16 stores, nothing else ----
        const size_t zb   = (size_t)(blockIdx.x - B);
        const size_t base = zb * (NT * ZPF4) + tid;
        const float4 z = make_float4(0.f, 0.f, 0.f, 0.f);
#pragma unroll
        for (int i = 0; i < ZPF4; ++i) out[base + (size_t)i * NT] = z;
        return;
    }

    // ---- per-row top-k path (verified round 3) ----
    const int b = blockIdx.x;
    const float4* __restrict__ x4 = (const float4*)(x + (size_t)b * NROW);

    hist[0][tid] = 0; hist[1][tid] = 0; hist[2][tid] = 0; hist[3][tid] = 0;
    if (tid == 0) { cnt = 0; suf[256] = 0; }

    unsigned u[64];
#pragma unroll
    for (int i = 0; i < 16; ++i) {
        float4 w = x4[i * NT + tid];
        u[4*i+0] = f2u(w.x); u[4*i+1] = f2u(w.y);
        u[4*i+2] = f2u(w.z); u[4*i+3] = f2u(w.w);
    }
    __syncthreads();

    const int wv = tid >> 6;
#pragma unroll
    for (int i = 0; i < 64; ++i) atomicAdd(&hist[wv][u[i] >> 24], 1u);
    __syncthreads();

    suf[tid] = hist[0][tid] + hist[1][tid] + hist[2][tid] + hist[3][tid];
    __syncthreads();

    // parallel inclusive suffix-sum: suf[t] = # values with top byte >= t
#pragma unroll
    for (int off = 1; off < 256; off <<= 1) {
        unsigned add = (tid + off < 256) ? suf[tid + off] : 0;
        __syncthreads();
        suf[tid] += add;
        __syncthreads();
    }
    if (suf[tid] >= KTOP && suf[tid + 1] < KTOP) selB = (unsigned)tid;  // unique
    __syncthreads();

    const unsigned thrU = selB << 24;
#pragma unroll
    for (int i = 0; i < 64; ++i) {
        if (u[i] >= thrU) {
            unsigned p = atomicAdd(&cnt, 1u);
            if (p < CAP) list[p] = u[i];
        }
    }
    __syncthreads();

    const int C = (int)min(cnt, (unsigned)CAP);   // >= 32 by construction
    // rank-sort: exact top-32, deterministic tie-break by list position
    for (int p = tid; p < C; p += NT) {
        unsigned v = list[p];
        int r = 0;
        for (int j = 0; j < C; ++j) {
            unsigned w = list[j];
            r += (w > v) || (w == v && j < p);
        }
        if (r < KTOP) tU[r] = v;
    }
    __syncthreads();
    if (tid < KTOP) { tFs[tid] = u2f(tU[tid]); svals[tid] = 0.0f; }
    __syncthreads();

    // x_m_sum: only x >= t[31] - 2eps can contribute; sweep register copy.
    const unsigned gU = f2u(tFs[KTOP - 1] - 2.0f * F_EPS);
#pragma unroll
    for (int i = 0; i < 64; ++i) {
        if (u[i] >= gU) {
            float vv = u2f(u[i]);
            for (int j = 0; j < KTOP; ++j) {
                float d  = vv - tFs[j];
                float xm = fmaxf(F_E2 - d * d, 0.0f) * F_INV_E2;  // 0 or 1 here
                if (xm > 0.0f) atomicAdd(&svals[j], xm);
            }
        }
    }
    __syncthreads();

    if (tid < KTOP)            ts[b * 2 * KTOP + tid] = tFs[tid];
    else if (tid < 2 * KTOP)   ts[b * 2 * KTOP + tid] = 1.0f - svals[tid - KTOP];
}

// One block per row: overwrite the 128-B output rows of candidate positions.
// Kernel boundary guarantees the zeros from kernel 1 land first.
__global__ __launch_bounds__(NT)
void fixup_kernel(const float* __restrict__ x, const float* __restrict__ ts,
                  float* __restrict__ out) {
    __shared__ float tsRow[2 * KTOP];
    const int b = blockIdx.x, tid = threadIdx.x;
    if (tid < 2 * KTOP) tsRow[tid] = ts[b * 2 * KTOP + tid];
    __syncthreads();
    const unsigned gU = f2u(tsRow[KTOP - 1] - 2.0f * F_EPS);
    const float4* __restrict__ x4 = (const float4*)(x + (size_t)b * NROW);

#pragma unroll 1
    for (int i = 0; i < 16; ++i) {
        float4 w = x4[i * NT + tid];
        float e[4] = {w.x, w.y, w.z, w.w};
#pragma unroll
        for (int c = 0; c < 4; ++c) {
            float vv = e[c];
            if (f2u(vv) >= gU) {               // rare: ~32 positions per row
                const int n = (i * NT + tid) * 4 + c;
                float4* o4 = (float4*)(out + ((size_t)b * NROW + n) * KTOP);
#pragma unroll
                for (int q = 0; q < 8; ++q) {
                    float4 o; float dd, mm;
                    dd = vv - tsRow[4*q+0]; mm = fmaxf(F_E2 - dd*dd, 0.f) * F_INV_E2; o.x = fmaxf(mm + tsRow[KTOP+4*q+0], 0.f);
                    dd = vv - tsRow[4*q+1]; mm = fmaxf(F_E2 - dd*dd, 0.f) * F_INV_E2; o.y = fmaxf(mm + tsRow[KTOP+4*q+1], 0.f);
                    dd = vv - tsRow[4*q+2]; mm = fmaxf(F_E2 - dd*dd, 0.f) * F_INV_E2; o.z = fmaxf(mm + tsRow[KTOP+4*q+2], 0.f);
                    dd = vv - tsRow[4*q+3]; mm = fmaxf(F_E2 - dd*dd, 0.f) * F_INV_E2; o.w = fmaxf(mm + tsRow[KTOP+4*q+3], 0.f);
                    o4[q] = o;
                }
            }
        }
    }
}

extern "C" void kernel_launch(void* const* d_in, const int* in_sizes, int n_in,
                              void* d_out, int out_size, void* d_ws, size_t ws_size,
                              hipStream_t stream) {
    const float* x = (const float*)d_in[0];
    float* out = (float*)d_out;
    const int B = in_sizes[0] / NROW;                // 128
    float* ts = (float*)d_ws;                        // B * 64 floats

    const int total_f4 = out_size / 4;               // 16,777,216
    const int ZBn = total_f4 / (NT * ZPF4);          // 4096 zero blocks

    topk_zero_kernel<<<B + ZBn, NT, 0, stream>>>(x, (float4*)out, ts, B);
    fixup_kernel<<<B, NT, 0, stream>>>(x, ts, out);
}